// Round 8
// baseline (148.071 us; speedup 1.0000x reference)
//
#include <hip/hip_runtime.h>
#include <hip/hip_bf16.h>

// AngleProtoLoss: loss = -mean_n logsoftmax(clip(cos(last_n,cent_k),1e-6)*w+b)[n,n]
// Identity: loss_n = ln2*(log2(sum_k 2^{z_nk}) - z_nn), z = clamp(cos*w*log2e); b cancels.
// k1: centroids+norms -> unit cent (bf16), w*log2e-prescaled unit last (bf16), fp32 z_nn.
// k2: R5-EXACT loop (best measured: 35.3us): grid (32,16) x 512 thr, 8 waves x 32 rows
//     (a[2][4]), 8 iters of 64-col slabs, 2x16KB LDS dbuf, XOR chunk swizzle, one-sided
//     exp-domain clamp. NEW: fused loss tail via waitcnt-only ticket (NO threadfence /
//     cache maintenance -- R1's buffer_wbl2 storm is avoided; tail reads via atomic
//     fetch_add(0) at the coherence point). k3 kernel deleted.
// PROBE (this round): second k2 launch with reps=2 (identical steady-state loop run
//     twice, ~70us) to force k2 above the 44us harness fills into rocprof top-5 WITH
//     counters. Pre-committed reading: VALUBusy>=50% -> epilogue-bound; both <25% ->
//     drain/schedule stall; LDS conflicts -> swizzle bug; FETCH>>14MB -> L2 problem.
// LEDGER: fill 44.5us fixed; non-k2 ~75.3us incl k3~4; k2: R0/4wave=34, R5=35.3,
//     R7(128-col slabs)=41.2 (drain scales with DMA volume; fewer barriers != faster).
// R1: per-block __threadfence()+ticket = 73us serialization. R3+R6: a[4][4] spills.

typedef __attribute__((ext_vector_type(8))) short short8;
typedef __attribute__((ext_vector_type(4))) float f32x4;

#define NSPK 8192
#define DEMB 128
#define MUTT 10
#define LOG2E 1.44269504088896340736f
#define LN2   0.69314718055994530942f

// workspace floats: [0,8192)=zdiag, [8192,16384)=zsum; then bf16 matrices; scratch after.
#define WS_ZDIAG 0
#define WS_ZSUM  8192
#define WS_LASTB 65536      // byte offset, 2 MB
#define WS_CENTB 2162688    // byte offset, 2 MB
#define WS_ZSUM2 1064960    // float idx: probe scratch zsum (never read)
#define WS_TICKET 1073152   // int idx (byte 4292608)

__global__ __launch_bounds__(256) void k1_prep(const float* __restrict__ x,
                                               const float* __restrict__ wp,
                                               float* __restrict__ W,
                                               __hip_bfloat16* __restrict__ lastb,
                                               __hip_bfloat16* __restrict__ centb) {
    const int wv = threadIdx.x >> 6;
    const int l  = threadIdx.x & 63;
    const int n  = blockIdx.x * 4 + wv;           // one wave per speaker
    if (blockIdx.x < 32) W[WS_ZSUM + blockIdx.x * 256 + threadIdx.x] = 0.f;
    if (blockIdx.x == 32 && threadIdx.x == 0) ((int*)W)[WS_TICKET] = 0;

    // flat 1280 floats per speaker; lane l, step i -> float4 at 64*i + l.
    // lanes 0..31: m = 2i ; lanes 32..63: m = 2i+1
    const float4* xr = (const float4*)(x + (size_t)n * (MUTT * DEMB)) + l;
    float4 v[5];
#pragma unroll
    for (int i = 0; i < 5; ++i) v[i] = xr[i * 64];

    float4 cs;
    cs.x = ((v[0].x + v[1].x) + (v[2].x + v[3].x)) + v[4].x;
    cs.y = ((v[0].y + v[1].y) + (v[2].y + v[3].y)) + v[4].y;
    cs.z = ((v[0].z + v[1].z) + (v[2].z + v[3].z)) + v[4].z;
    cs.w = ((v[0].w + v[1].w) + (v[2].w + v[3].w)) + v[4].w;
    cs.x += __shfl_xor(cs.x, 32);
    cs.y += __shfl_xor(cs.y, 32);
    cs.z += __shfl_xor(cs.z, 32);
    cs.w += __shfl_xor(cs.w, 32);
    float4 cent;
    cent.x = cs.x * 0.1f; cent.y = cs.y * 0.1f; cent.z = cs.z * 0.1f; cent.w = cs.w * 0.1f;

    // last row (m=9) lives in v[4] of lanes >= 32; mirror into lanes < 32
    float4 lv = v[4];
    {
        const float tx = __shfl_xor(lv.x, 32);
        const float ty = __shfl_xor(lv.y, 32);
        const float tz = __shfl_xor(lv.z, 32);
        const float tw = __shfl_xor(lv.w, 32);
        if (l < 32) { lv.x = tx; lv.y = ty; lv.z = tz; lv.w = tw; }
    }

    float sl = lv.x * lv.x + lv.y * lv.y + lv.z * lv.z + lv.w * lv.w;
    float sc = cent.x * cent.x + cent.y * cent.y + cent.z * cent.z + cent.w * cent.w;
    float dp = lv.x * cent.x + lv.y * cent.y + lv.z * cent.z + lv.w * cent.w;
#pragma unroll
    for (int off = 1; off < 32; off <<= 1) {
        sl += __shfl_xor(sl, off);
        sc += __shfl_xor(sc, off);
        dp += __shfl_xor(dp, off);
    }
    const float il = rsqrtf(sl), ic = rsqrtf(sc);
    const float scale = wp[0] * LOG2E;
    const float as = il * scale;                  // prescale last by w*log2e

    const float  f  = (l < 32) ? as : ic;
    const float4 s4 = (l < 32) ? lv : cent;
    __hip_bfloat16* bp = ((l < 32) ? lastb : centb) + (size_t)n * DEMB + 4 * (l & 31);
    union { __hip_bfloat162 h[2]; uint2 u; } pk;
    pk.h[0].x = __float2bfloat16(s4.x * f);
    pk.h[0].y = __float2bfloat16(s4.y * f);
    pk.h[1].x = __float2bfloat16(s4.z * f);
    pk.h[1].y = __float2bfloat16(s4.w * f);
    *(uint2*)bp = pk.u;

    if (l == 0) {
        const float lo = scale >= 0.f ? 1e-6f * scale : -INFINITY;
        const float hi = scale >= 0.f ? INFINITY : 1e-6f * scale;
        W[WS_ZDIAG + n] = fminf(fmaxf(dp * il * ic * scale, lo), hi);
    }
}

// grid (32,16) x 512 threads: 256-row block x 512-col chunk. 8 waves; wave owns 32 rows.
// reps: probe runs the identical steady-state loop reps times (real launch: reps=1).
__global__ __launch_bounds__(512, 4) void k2_main(
        const __hip_bfloat16* __restrict__ lastb,
        const __hip_bfloat16* __restrict__ centb,
        const float* __restrict__ wp,
        float* __restrict__ zsum,
        const float* __restrict__ zdiag,
        int* __restrict__ ticket,
        float* __restrict__ out,
        int reps) {
    const int tid  = threadIdx.x;
    const int lane = tid & 63;
    const int wv   = tid >> 6;                // 0..7
    const int quad = lane >> 4;
    const int l16  = lane & 15;
    const int R0   = blockIdx.x * 256;
    const int C0   = blockIdx.y * 512;
    const float scale = wp[0] * LOG2E;
    // clamp in exp domain (2^z monotone). scale>=0: e >= c0; scale<0: e <= c0.
    const float c0  = __builtin_amdgcn_exp2f(1e-6f * scale);
    const bool  pos = (scale >= 0.f);

    __shared__ uint4 Bs4[2048];   // 2 x 16 KB double buffer, XOR chunk-swizzled
    __shared__ float redw[8];
    __shared__ int   lastFlag;
    char* Bsc = (char*)Bs4;

    // staging: wave wv stages rows wv*8 + i*4 + quad (i=0,1); LDS image = R0 layout
#pragma unroll
    for (int i = 0; i < 2; ++i) {
        const int rr = wv * 8 + i * 4 + quad;
        const int c  = l16 ^ (rr & 15);
        const char* src = (const char*)centb + ((size_t)(C0 + rr) << 8) + (c << 4);
        char* dst = Bsc + (wv * 2048 + i * 1024 + lane * 16);
        __builtin_amdgcn_global_load_lds(
            (const __attribute__((address_space(1))) unsigned int*)src,
            (__attribute__((address_space(3))) unsigned int*)dst, 16, 0, 0);
    }

    // A fragments (held whole kernel): rows R0 + wv*32 + rt*16 + l16, k = quad*8 + kc*32
    short8 a[2][4];
    {
        const short* ap = (const short*)lastb + (size_t)(R0 + wv * 32 + l16) * DEMB + quad * 8;
#pragma unroll
        for (int rt = 0; rt < 2; ++rt)
#pragma unroll
            for (int kc = 0; kc < 4; ++kc)
                a[rt][kc] = *(const short8*)(ap + rt * 16 * DEMB + kc * 32);
    }

    // swizzled B-fragment byte offsets within a 16-row ntile: row=l16, chunk=(quad+4kc)^l16
    int roff[4];
#pragma unroll
    for (int kc = 0; kc < 4; ++kc)
        roff[kc] = l16 * 256 + (((quad + 4 * kc) ^ l16) << 4);

    float racc[2][4] = {{0.f}};

    for (int rep = 0; rep < reps; ++rep) {
        for (int it = 0; it < 8; ++it) {
            // drains vmcnt -> DMA(it) landed; also all waves done reading buf[(it+1)&1]
            __syncthreads();
            if (it < 7 || rep + 1 < reps) {
                const int itn = (it + 1) & 7;
                const int c0n = C0 + itn * 64;
                char* bufn = Bsc + ((it + 1) & 1) * 16384;
#pragma unroll
                for (int i = 0; i < 2; ++i) {
                    const int rr = wv * 8 + i * 4 + quad;
                    const int c  = l16 ^ (rr & 15);
                    const char* src = (const char*)centb + ((size_t)(c0n + rr) << 8) + (c << 4);
                    char* dst = bufn + (wv * 2048 + i * 1024 + lane * 16);
                    __builtin_amdgcn_global_load_lds(
                        (const __attribute__((address_space(1))) unsigned int*)src,
                        (__attribute__((address_space(3))) unsigned int*)dst, 16, 0, 0);
                }
            }
            const char* buf = Bsc + (it & 1) * 16384;
#pragma unroll
            for (int nt = 0; nt < 4; ++nt) {
                short8 b[4];
#pragma unroll
                for (int kc = 0; kc < 4; ++kc)
                    b[kc] = *(const short8*)(buf + nt * 4096 + roff[kc]);
                if (pos) {   // wave-uniform: single-sided clamp
#pragma unroll
                    for (int rt = 0; rt < 2; ++rt) {
                        f32x4 acc = {0.f, 0.f, 0.f, 0.f};
#pragma unroll
                        for (int kc = 0; kc < 4; ++kc)
                            acc = __builtin_amdgcn_mfma_f32_16x16x32_bf16(a[rt][kc], b[kc], acc, 0, 0, 0);
#pragma unroll
                        for (int r = 0; r < 4; ++r)
                            racc[rt][r] += fmaxf(__builtin_amdgcn_exp2f(acc[r]), c0);
                    }
                } else {
#pragma unroll
                    for (int rt = 0; rt < 2; ++rt) {
                        f32x4 acc = {0.f, 0.f, 0.f, 0.f};
#pragma unroll
                        for (int kc = 0; kc < 4; ++kc)
                            acc = __builtin_amdgcn_mfma_f32_16x16x32_bf16(a[rt][kc], b[kc], acc, 0, 0, 0);
#pragma unroll
                        for (int r = 0; r < 4; ++r)
                            racc[rt][r] += fminf(__builtin_amdgcn_exp2f(acc[r]), c0);
                    }
                }
            }
        }
    }
    // reduce row sums over the 16 l16-lanes holding the same rows
#pragma unroll
    for (int off = 1; off < 16; off <<= 1)
#pragma unroll
        for (int rt = 0; rt < 2; ++rt)
#pragma unroll
            for (int r = 0; r < 4; ++r)
                racc[rt][r] += __shfl_xor(racc[rt][r], off);
    if (l16 == 0) {
#pragma unroll
        for (int rt = 0; rt < 2; ++rt)
#pragma unroll
            for (int r = 0; r < 4; ++r)
                atomicAdd(&zsum[R0 + wv * 32 + rt * 16 + quad * 4 + r], racc[rt][r]);
    }

    // ---- fused loss tail: waitcnt-only ticket (no threadfence / cache maintenance) ----
    if (out != nullptr) {
        // own wave's zsum atomics complete at the coherence point:
        asm volatile("s_waitcnt vmcnt(0)" ::: "memory");
        __syncthreads();                       // => all 8 waves' atomics complete
        if (tid == 0) {
            const int prev = __hip_atomic_fetch_add(ticket, 1, __ATOMIC_RELAXED,
                                                    __HIP_MEMORY_SCOPE_AGENT);
            lastFlag = (prev == 32 * 16 - 1);
        }
        __syncthreads();
        if (lastFlag) {                        // block-uniform: last-finishing block
            float v = 0.f;
            for (int n = tid; n < NSPK; n += 512) {
                // fetch_add(0) = coherence-point read of the fully-accumulated zsum
                const float s = __hip_atomic_fetch_add(&zsum[n], 0.f,
                                                       __ATOMIC_RELAXED,
                                                       __HIP_MEMORY_SCOPE_AGENT);
                v += __log2f(s) - zdiag[n];
            }
#pragma unroll
            for (int off = 1; off < 64; off <<= 1) v += __shfl_xor(v, off);
            if (lane == 0) redw[wv] = v;
            __syncthreads();
            if (tid == 0) {
                float t = 0.f;
#pragma unroll
                for (int i = 0; i < 8; ++i) t += redw[i];
                out[0] = t * (LN2 / (float)NSPK);
            }
        }
    }
}

extern "C" void kernel_launch(void* const* d_in, const int* in_sizes, int n_in,
                              void* d_out, int out_size, void* d_ws, size_t ws_size,
                              hipStream_t stream) {
    const float* x = (const float*)d_in[0];
    const float* w = (const float*)d_in[1];
    // b (d_in[2]) cancels analytically — unused.
    float* W = (float*)d_ws;
    __hip_bfloat16* lastb = (__hip_bfloat16*)((char*)d_ws + WS_LASTB);
    __hip_bfloat16* centb = (__hip_bfloat16*)((char*)d_ws + WS_CENTB);

    k1_prep<<<NSPK / 4, 256, 0, stream>>>(x, w, W, lastb, centb);
    k2_main<<<dim3(32, 16), 512, 0, stream>>>(lastb, centb, w, W + WS_ZSUM,
                                              W + WS_ZDIAG, (int*)W + WS_TICKET,
                                              (float*)d_out, 1);
    // PROBE (this round only): reps=2 pushes k2 (~70us) above the 44us fills so its
    // steady-state counters land in rocprof top-5. Writes to scratch zsum2; no tail.
    k2_main<<<dim3(32, 16), 512, 0, stream>>>(lastb, centb, w, W + WS_ZSUM2,
                                              W + WS_ZDIAG, nullptr, nullptr, 2);
}